// Round 6
// baseline (555.559 us; speedup 1.0000x reference)
//
#include <hip/hip_runtime.h>

#define N_ 32
#define C_ 128
#define K_ 64
#define S_ 16384
#define TS 64                 // s-positions per tile
#define NBPN 32               // blocks per image (1024 total = 4/CU exactly)
#define NTILES (S_/TS)        // 256 tiles per image
#define TPB (NTILES/NBPN)     // 8 tiles per block, uniform
#define NBLK (N_*NBPN)
#define XS 128                // sXT stride (halfs) — XOR-swizzled, no pad
#define WS 128                // sW stride — XOR-swizzled, no pad
#define PS 64                 // sP stride — granule-swizzled, no pad
#define EPS 1e-12f

typedef __attribute__((ext_vector_type(8))) _Float16 half8;
typedef __attribute__((ext_vector_type(4))) _Float16 half4;
typedef __attribute__((ext_vector_type(4))) float floatx4;

// sW swizzle (row-keyed 16-half blocks), stride 128.
__device__ __forceinline__ int swz(int row, int c) {
  return (((c >> 4) ^ (row & 7)) << 4) | (c & 15);
}

// Raw barrier: LDS visibility only (lgkmcnt(0)); global loads stay in flight.
#define BAR_LDS()                                            \
  do {                                                       \
    __builtin_amdgcn_sched_barrier(0);                       \
    asm volatile("s_waitcnt lgkmcnt(0)" ::: "memory");       \
    __builtin_amdgcn_s_barrier();                            \
    __builtin_amdgcn_sched_barrier(0);                       \
  } while (0)

// ---------------------------------------------------------------------------
// Single-x-read fused kernel, 4 blocks/CU (LDS = exactly 40 KB).
// waves_per_eu pinned to (4,4): 16 waves/CU matches the LDS cap, so the
// allocator gets the full 128-VGPR budget (R5's 64-VGPR clamp caused a
// 140 MB/dispatch spill storm).
// sXT element (s,c) at: s*128 + blk*16 + (c&15), blk = (c>>4)^((s>>3)&7)^(s&7)
// sP  element (kc,s) at: kc*64 + ((s>>3)^(kc&7))*8 + (s&7)
// ---------------------------------------------------------------------------
template <bool SLAB>
__global__ __attribute__((amdgpu_waves_per_eu(4, 4))) __launch_bounds__(256)
void vlad_main(
    const float* __restrict__ x, const float* __restrict__ w,
    float* __restrict__ vlad_out, float* __restrict__ asum_out) {
  __shared__ _Float16 sXT[TS * XS];   // 16384 B
  __shared__ _Float16 sW[K_ * WS];    // 16384 B
  __shared__ _Float16 sP[K_ * PS];    // 8192 B   => total 40960 B
  float* sRed = (float*)sXT;          // aliased: sXT dead after last phase B

  const int tid = threadIdx.x;
  const int lane = tid & 63;
  const int wv = tid >> 6;
  const int lm = lane & 15;
  const int quad = lane >> 4;

  const int bid = blockIdx.x;
  const int n = bid >> 5;             // bid / NBPN
  const int j = bid & 31;             // bid % NBPN
  const int ts = j * TPB;
  const int te = ts + TPB;

  // W -> LDS once per block
  for (int idx = tid; idx < K_ * C_; idx += 256) {
    int kc = idx >> 7, c = idx & 127;
    sW[kc * WS + swz(kc, c)] = (_Float16)w[idx];
  }

  floatx4 acc[2][4];
#pragma unroll
  for (int i = 0; i < 2; ++i)
#pragma unroll
    for (int k = 0; k < 4; ++k) acc[i][k] = (floatx4){0.f, 0.f, 0.f, 0.f};
  float accA[4] = {0.f, 0.f, 0.f, 0.f};

  const float* xn = x + (size_t)n * C_ * S_;
  const float* xrow[2];
  xrow[0] = xn + (size_t)((2 * wv + 0) * 16 + lm) * S_;
  xrow[1] = xn + (size_t)((2 * wv + 1) * 16 + lm) * S_;

  // ---- prologue: load gx for the first tile ----
  float4 gx[2][2][2];   // [ci][slab-half][pair of float4 = 8 s-values]
#pragma unroll
  for (int ci = 0; ci < 2; ++ci)
#pragma unroll
    for (int sl = 0; sl < 2; ++sl) {
      const float* p = xrow[ci] + ts * TS + sl * 32 + quad * 8;
      gx[ci][sl][0] = *(const float4*)p;
      gx[ci][sl][1] = *(const float4*)(p + 4);
    }

  __syncthreads();  // sW ready (cold path; full drain fine here)

  for (int t = ts; t < te; ++t) {
    // ---- A: cvt gx -> hx (these ARE the GEMM2 B-frags), scatter into sXT ----
    half8 hx[2][2];
#pragma unroll
    for (int ci = 0; ci < 2; ++ci)
#pragma unroll
      for (int sl = 0; sl < 2; ++sl) {
        half8 h;
        h[0] = (_Float16)gx[ci][sl][0].x; h[1] = (_Float16)gx[ci][sl][0].y;
        h[2] = (_Float16)gx[ci][sl][0].z; h[3] = (_Float16)gx[ci][sl][0].w;
        h[4] = (_Float16)gx[ci][sl][1].x; h[5] = (_Float16)gx[ci][sl][1].y;
        h[6] = (_Float16)gx[ci][sl][1].z; h[7] = (_Float16)gx[ci][sl][1].w;
        hx[ci][sl] = h;
      }
    // scatter-transpose: element (s = sl*32+quad*8+jj, c = (2wv+ci)*16+lm)
#pragma unroll
    for (int ci = 0; ci < 2; ++ci) {
#pragma unroll
      for (int sl = 0; sl < 2; ++sl) {
        const int key = sl * 4 + quad;              // (s>>3)&7
        const int cblk = 2 * wv + ci;               // c>>4
        const int base = (sl * 32 + quad * 8) * XS + lm;
#pragma unroll
        for (int jj = 0; jj < 8; ++jj)
          sXT[base + jj * XS + (((cblk ^ key ^ jj)) << 4)] = hx[ci][sl][jj];
      }
    }
    BAR_LDS();  // post-A (sXT ready)

    // ---- B: GEMM1 logits = mfma(A = x^T rows, B = W cols) ----
    floatx4 D[4];
#pragma unroll
    for (int k = 0; k < 4; ++k) D[k] = (floatx4){0.f, 0.f, 0.f, 0.f};
    const int srow = wv * 16 + lm;
    const int rk = ((srow >> 3) & 7) ^ (srow & 7);
#pragma unroll
    for (int ks = 0; ks < 4; ++ks) {
      const int blk = (ks * 2 + (quad >> 1)) ^ rk;
      half8 Af = *(const half8*)&sXT[srow * XS + blk * 16 + (quad & 1) * 8];
#pragma unroll
      for (int kt = 0; kt < 4; ++kt) {
        const int krow = kt * 16 + lm;
        half8 Wf = *(const half8*)&sW[krow * WS + swz(krow, ks * 32 + quad * 8)];
        D[kt] = __builtin_amdgcn_mfma_f32_16x16x32_f16(Af, Wf, D[kt], 0, 0, 0);
      }
    }

    // ---- C: softmax over all 64 kc per s-row (no max-sub; |logit| <~ 7) ----
#pragma unroll
    for (int r = 0; r < 4; ++r) {
      float e0 = __expf(D[0][r]), e1 = __expf(D[1][r]),
            e2 = __expf(D[2][r]), e3 = __expf(D[3][r]);
      float sum = e0 + e1 + e2 + e3;
      sum += __shfl_xor(sum, 1);
      sum += __shfl_xor(sum, 2);
      sum += __shfl_xor(sum, 4);
      sum += __shfl_xor(sum, 8);
      float inv = 1.f / sum;
      D[0][r] = e0 * inv; D[1][r] = e1 * inv;
      D[2][r] = e2 * inv; D[3][r] = e3 * inv;
    }
    // sP write: kc = kt*16+lm, s0 = wv*16+quad*4 (granule-swizzled)
#pragma unroll
    for (int kt = 0; kt < 4; ++kt) {
      accA[kt] += D[kt][0] + D[kt][1] + D[kt][2] + D[kt][3];
      half4 hp = {(_Float16)D[kt][0], (_Float16)D[kt][1],
                  (_Float16)D[kt][2], (_Float16)D[kt][3]};
      const int pg = (wv * 2 + (quad >> 1)) ^ (lm & 7);
      *(half4*)&sP[(kt * 16 + lm) * PS + pg * 8 + (quad & 1) * 4] = hp;
    }

    // ---- issue next tile's gx loads here (short live-range; flight covered
    //      by barrier wait + phase D + next-tile cvt) ----
    if (t + 1 < te) {
#pragma unroll
      for (int ci = 0; ci < 2; ++ci)
#pragma unroll
        for (int sl = 0; sl < 2; ++sl) {
          const float* p = xrow[ci] + (t + 1) * TS + sl * 32 + quad * 8;
          gx[ci][sl][0] = *(const float4*)p;
          gx[ci][sl][1] = *(const float4*)(p + 4);
        }
    }
    BAR_LDS();  // post-C (sP ready; gx loads stay in flight)

    // ---- D: GEMM2 swapped: acc = mfma(A = P, B = x^T) — x from hx regs ----
#pragma unroll
    for (int sl = 0; sl < 2; ++sl) {
      half8 Pf[4];
#pragma unroll
      for (int kt = 0; kt < 4; ++kt) {
        const int pg = (sl * 4 + quad) ^ (lm & 7);
        Pf[kt] = *(const half8*)&sP[(kt * 16 + lm) * PS + pg * 8];
      }
#pragma unroll
      for (int ci = 0; ci < 2; ++ci)
#pragma unroll
        for (int kt = 0; kt < 4; ++kt)
          acc[ci][kt] = __builtin_amdgcn_mfma_f32_16x16x32_f16(
              Pf[kt], hx[ci][sl], acc[ci][kt], 0, 0, 0);
    }
  }

  // ---- epilogue: vlad partials. Swapped D layout:
  //      kc = kt*16 + quad*4 + r,  c = (2wv+ci)*16 + lm ----
  float* vb = vlad_out + (SLAB ? (size_t)bid : (size_t)n) * (K_ * C_);
#pragma unroll
  for (int ci = 0; ci < 2; ++ci) {
    const int c = (2 * wv + ci) * 16 + lm;
#pragma unroll
    for (int kt = 0; kt < 4; ++kt) {
      const int kc0 = kt * 16 + quad * 4;
#pragma unroll
      for (int r = 0; r < 4; ++r) {
        if (SLAB) {
          vb[(size_t)(kc0 + r) * C_ + c] = acc[ci][kt][r];
        } else {
          atomicAdd(vb + (size_t)(kc0 + r) * C_ + c, acc[ci][kt][r]);
        }
      }
    }
  }

  // ---- epilogue: asum (reduce quads via shfl, waves via sRed on sXT) ----
#pragma unroll
  for (int kt = 0; kt < 4; ++kt) {
    float v = accA[kt];
    v += __shfl_xor(v, 16);
    v += __shfl_xor(v, 32);
    if (quad == 0) sRed[wv * K_ + kt * 16 + lm] = v;
  }
  __syncthreads();
  if (tid < K_) {
    float s = sRed[tid] + sRed[K_ + tid] + sRed[2 * K_ + tid] + sRed[3 * K_ + tid];
    if (SLAB) asum_out[(size_t)bid * K_ + tid] = s;
    else atomicAdd(asum_out + n * K_ + tid, s);
  }
}

// ---------------------------------------------------------------------------
// Kernel 2: reduce slabs, subtract asum*centroid, intra-normalize, gnorm
// ---------------------------------------------------------------------------
template <bool SLAB>
__global__ __launch_bounds__(128) void vlad_intra(
    const float* __restrict__ vlad_in, const float* __restrict__ asum_in,
    const float* __restrict__ cent, float* __restrict__ vlad_norm,
    float* __restrict__ gnorm) {
  const int bid = blockIdx.x;
  const int n = bid >> 6, k = bid & 63;
  const int c = threadIdx.x;

  float v, a;
  if (SLAB) {
    v = 0.f; a = 0.f;
#pragma unroll 4
    for (int ch = 0; ch < NBPN; ++ch) {
      v += vlad_in[((size_t)(n * NBPN + ch) * K_ + k) * C_ + c];
      a += asum_in[(n * NBPN + ch) * K_ + k];
    }
  } else {
    v = vlad_in[((size_t)(n * K_ + k)) * C_ + c];
    a = asum_in[n * K_ + k];
  }
  v -= a * cent[k * C_ + c];

  float ss = v * v;
  ss += __shfl_xor(ss, 1);  ss += __shfl_xor(ss, 2);  ss += __shfl_xor(ss, 4);
  ss += __shfl_xor(ss, 8);  ss += __shfl_xor(ss, 16); ss += __shfl_xor(ss, 32);
  __shared__ float red[2];
  if ((threadIdx.x & 63) == 0) red[threadIdx.x >> 6] = ss;
  __syncthreads();
  float total = red[0] + red[1];
  float nrm = fmaxf(sqrtf(total), EPS);
  vlad_norm[((size_t)(n * K_ + k)) * C_ + c] = v / nrm;
  if (threadIdx.x == 0) atomicAdd(gnorm + n, total / (nrm * nrm));
}

// ---------------------------------------------------------------------------
// Kernel 3: global L2 normalize per n
// ---------------------------------------------------------------------------
__global__ __launch_bounds__(256) void vlad_final(
    const float* __restrict__ vlad_norm, const float* __restrict__ gnorm,
    float* __restrict__ out) {
  const int idx = blockIdx.x * 256 + threadIdx.x;
  if (idx >= N_ * K_ * C_) return;
  float g = gnorm[idx >> 13];
  out[idx] = vlad_norm[idx] / fmaxf(sqrtf(g), EPS);
}

extern "C" void kernel_launch(void* const* d_in, const int* in_sizes, int n_in,
                              void* d_out, int out_size, void* d_ws, size_t ws_size,
                              hipStream_t stream) {
  const float* x    = (const float*)d_in[0];
  const float* w    = (const float*)d_in[1];
  const float* cent = (const float*)d_in[2];
  float* out = (float*)d_out;

  const size_t slab_f = (size_t)NBLK * K_ * C_;    // 8,388,608 floats (33.5 MB)
  const size_t asum_f = (size_t)NBLK * K_;         // 65,536
  const size_t norm_f = (size_t)N_ * K_ * C_;      // 262,144
  const size_t need = (slab_f + asum_f + norm_f + N_) * sizeof(float);

  if (ws_size >= need) {
    float* slab  = (float*)d_ws;
    float* asums = slab + slab_f;
    float* vnorm = asums + asum_f;
    float* gnorm = vnorm + norm_f;
    hipMemsetAsync(gnorm, 0, N_ * sizeof(float), stream);
    vlad_main<true><<<dim3(NBLK), dim3(256), 0, stream>>>(x, w, slab, asums);
    vlad_intra<true><<<dim3(N_ * K_), dim3(128), 0, stream>>>(slab, asums, cent, vnorm, gnorm);
    vlad_final<<<dim3((N_ * K_ * C_ + 255) / 256), dim3(256), 0, stream>>>(vnorm, gnorm, out);
  } else {
    float* vlad_acc = (float*)d_ws;
    float* asum_g   = vlad_acc + norm_f;
    float* gnorm    = asum_g + N_ * K_;
    hipMemsetAsync(d_ws, 0, (norm_f + N_ * K_ + N_) * sizeof(float), stream);
    vlad_main<false><<<dim3(NBLK), dim3(256), 0, stream>>>(x, w, vlad_acc, asum_g);
    vlad_intra<false><<<dim3(N_ * K_), dim3(128), 0, stream>>>(vlad_acc, asum_g, cent, vlad_acc, gnorm);
    vlad_final<<<dim3((N_ * K_ * C_ + 255) / 256), dim3(256), 0, stream>>>(vlad_acc, gnorm, out);
  }
}

// Round 7
// 399.728 us; speedup vs baseline: 1.3898x; 1.3898x over previous
//
#include <hip/hip_runtime.h>

#define N_ 32
#define C_ 128
#define K_ 64
#define S_ 16384
#define TS 64                 // s-positions per tile
#define NBPN 32               // blocks per image (1024 blocks, 8 tiles uniform)
#define NTILES (S_/TS)        // 256 tiles per image
#define TPB (NTILES/NBPN)     // 8 tiles per block
#define NBLK (N_*NBPN)
#define XS 128                // sXT stride (halfs) — XOR-swizzled
#define WS 128                // sW stride — XOR-swizzled
#define PS 64                 // sP stride — granule-swizzled
#define EPS 1e-12f

typedef __attribute__((ext_vector_type(8))) _Float16 half8;
typedef __attribute__((ext_vector_type(4))) _Float16 half4;
typedef __attribute__((ext_vector_type(4))) float floatx4;

// sW swizzle (row-keyed 16-half blocks), stride 128.
__device__ __forceinline__ int swz(int row, int c) {
  return (((c >> 4) ^ (row & 7)) << 4) | (c & 15);
}

// Raw barrier: LDS visibility only (lgkmcnt(0)); global loads stay in flight.
#define BAR_LDS()                                            \
  do {                                                       \
    __builtin_amdgcn_sched_barrier(0);                       \
    asm volatile("s_waitcnt lgkmcnt(0)" ::: "memory");       \
    __builtin_amdgcn_s_barrier();                            \
    __builtin_amdgcn_sched_barrier(0);                       \
  } while (0)

// ---------------------------------------------------------------------------
// Single-x-read fused kernel. LDS deliberately padded to 48 KB (3 blocks/CU):
// at 40 KB (4 blocks/CU) the backend's occupancy heuristic clamps the
// allocator to 64 VGPRs and spills ~140-450 MB/dispatch to scratch
// (R5/R6 measured); at >=45 KB it grants the full (256,4) budget of 128.
// sXT element (s,c) at: s*128 + blk*16 + (c&15), blk = (c>>4)^((s>>3)&7)^(s&7)
// sP  element (kc,s) at: kc*64 + ((s>>3)^(kc&7))*8 + (s&7)
// (both validated in R5: bank conflicts 2.29M -> 0.52M)
// ---------------------------------------------------------------------------
template <bool SLAB>
__global__ __launch_bounds__(256, 4) void vlad_main(
    const float* __restrict__ x, const float* __restrict__ w,
    float* __restrict__ vlad_out, float* __restrict__ asum_out) {
  __shared__ _Float16 sXT[TS * XS];   // 16384 B
  __shared__ _Float16 sW[K_ * WS];    // 16384 B
  __shared__ _Float16 sP[K_ * PS];    // 8192 B
  __shared__ float sRed[2048];        // 8192 B  => total 49152 B (3 blk/CU)

  const int tid = threadIdx.x;
  const int lane = tid & 63;
  const int wv = tid >> 6;
  const int lm = lane & 15;
  const int quad = lane >> 4;

  const int bid = blockIdx.x;
  const int n = bid >> 5;             // bid / NBPN
  const int j = bid & 31;             // bid % NBPN
  const int ts = j * TPB;
  const int te = ts + TPB;

  // W -> LDS once per block
  for (int idx = tid; idx < K_ * C_; idx += 256) {
    int kc = idx >> 7, c = idx & 127;
    sW[kc * WS + swz(kc, c)] = (_Float16)w[idx];
  }

  floatx4 acc[2][4];
#pragma unroll
  for (int i = 0; i < 2; ++i)
#pragma unroll
    for (int k = 0; k < 4; ++k) acc[i][k] = (floatx4){0.f, 0.f, 0.f, 0.f};
  float accA[4] = {0.f, 0.f, 0.f, 0.f};

  const float* xn = x + (size_t)n * C_ * S_;
  const float* xrow[2];
  xrow[0] = xn + (size_t)((2 * wv + 0) * 16 + lm) * S_;
  xrow[1] = xn + (size_t)((2 * wv + 1) * 16 + lm) * S_;

  // ---- prologue: load gx for the first tile ----
  float4 gx[2][2][2];   // [ci][slab-half][pair of float4 = 8 s-values]
#pragma unroll
  for (int ci = 0; ci < 2; ++ci)
#pragma unroll
    for (int sl = 0; sl < 2; ++sl) {
      const float* p = xrow[ci] + ts * TS + sl * 32 + quad * 8;
      gx[ci][sl][0] = *(const float4*)p;
      gx[ci][sl][1] = *(const float4*)(p + 4);
    }

  __syncthreads();  // sW ready (cold path; full drain fine here)

  for (int t = ts; t < te; ++t) {
    // ---- A: cvt gx -> hx (these ARE the GEMM2 B-frags), scatter into sXT ----
    half8 hx[2][2];
#pragma unroll
    for (int ci = 0; ci < 2; ++ci)
#pragma unroll
      for (int sl = 0; sl < 2; ++sl) {
        half8 h;
        h[0] = (_Float16)gx[ci][sl][0].x; h[1] = (_Float16)gx[ci][sl][0].y;
        h[2] = (_Float16)gx[ci][sl][0].z; h[3] = (_Float16)gx[ci][sl][0].w;
        h[4] = (_Float16)gx[ci][sl][1].x; h[5] = (_Float16)gx[ci][sl][1].y;
        h[6] = (_Float16)gx[ci][sl][1].z; h[7] = (_Float16)gx[ci][sl][1].w;
        hx[ci][sl] = h;
      }
    // scatter-transpose: element (s = sl*32+quad*8+jj, c = (2wv+ci)*16+lm)
#pragma unroll
    for (int ci = 0; ci < 2; ++ci) {
#pragma unroll
      for (int sl = 0; sl < 2; ++sl) {
        const int key = sl * 4 + quad;              // (s>>3)&7
        const int cblk = 2 * wv + ci;               // c>>4
        const int base = (sl * 32 + quad * 8) * XS + lm;
#pragma unroll
        for (int jj = 0; jj < 8; ++jj)
          sXT[base + jj * XS + (((cblk ^ key ^ jj)) << 4)] = hx[ci][sl][jj];
      }
    }

    // ---- issue next tile's gx loads: full-tile flight before consumption ----
    if (t + 1 < te) {
#pragma unroll
      for (int ci = 0; ci < 2; ++ci)
#pragma unroll
        for (int sl = 0; sl < 2; ++sl) {
          const float* p = xrow[ci] + (t + 1) * TS + sl * 32 + quad * 8;
          gx[ci][sl][0] = *(const float4*)p;
          gx[ci][sl][1] = *(const float4*)(p + 4);
        }
    }
    BAR_LDS();  // post-A (sXT ready; gx loads stay in flight)

    // ---- B: GEMM1 logits = mfma(A = x^T rows, B = W cols) ----
    floatx4 D[4];
#pragma unroll
    for (int k = 0; k < 4; ++k) D[k] = (floatx4){0.f, 0.f, 0.f, 0.f};
    const int srow = wv * 16 + lm;
    const int rk = ((srow >> 3) & 7) ^ (srow & 7);
    __builtin_amdgcn_s_setprio(1);
#pragma unroll
    for (int ks = 0; ks < 4; ++ks) {
      const int blk = (ks * 2 + (quad >> 1)) ^ rk;
      half8 Af = *(const half8*)&sXT[srow * XS + blk * 16 + (quad & 1) * 8];
#pragma unroll
      for (int kt = 0; kt < 4; ++kt) {
        const int krow = kt * 16 + lm;
        half8 Wf = *(const half8*)&sW[krow * WS + swz(krow, ks * 32 + quad * 8)];
        D[kt] = __builtin_amdgcn_mfma_f32_16x16x32_f16(Af, Wf, D[kt], 0, 0, 0);
      }
    }
    __builtin_amdgcn_s_setprio(0);

    // ---- C: softmax over all 64 kc per s-row (no max-sub; |logit| <~ 7) ----
#pragma unroll
    for (int r = 0; r < 4; ++r) {
      float e0 = __expf(D[0][r]), e1 = __expf(D[1][r]),
            e2 = __expf(D[2][r]), e3 = __expf(D[3][r]);
      float sum = e0 + e1 + e2 + e3;
      sum += __shfl_xor(sum, 1);
      sum += __shfl_xor(sum, 2);
      sum += __shfl_xor(sum, 4);
      sum += __shfl_xor(sum, 8);
      float inv = 1.f / sum;
      D[0][r] = e0 * inv; D[1][r] = e1 * inv;
      D[2][r] = e2 * inv; D[3][r] = e3 * inv;
    }
    // sP write: kc = kt*16+lm, s0 = wv*16+quad*4 (granule-swizzled)
#pragma unroll
    for (int kt = 0; kt < 4; ++kt) {
      accA[kt] += D[kt][0] + D[kt][1] + D[kt][2] + D[kt][3];
      half4 hp = {(_Float16)D[kt][0], (_Float16)D[kt][1],
                  (_Float16)D[kt][2], (_Float16)D[kt][3]};
      const int pg = (wv * 2 + (quad >> 1)) ^ (lm & 7);
      *(half4*)&sP[(kt * 16 + lm) * PS + pg * 8 + (quad & 1) * 4] = hp;
    }
    BAR_LDS();  // post-C (sP ready; gx loads still in flight)

    // ---- D: GEMM2 swapped: acc = mfma(A = P, B = x^T) — x from hx regs ----
    __builtin_amdgcn_s_setprio(1);
#pragma unroll
    for (int sl = 0; sl < 2; ++sl) {
      half8 Pf[4];
#pragma unroll
      for (int kt = 0; kt < 4; ++kt) {
        const int pg = (sl * 4 + quad) ^ (lm & 7);
        Pf[kt] = *(const half8*)&sP[(kt * 16 + lm) * PS + pg * 8];
      }
#pragma unroll
      for (int ci = 0; ci < 2; ++ci)
#pragma unroll
        for (int kt = 0; kt < 4; ++kt)
          acc[ci][kt] = __builtin_amdgcn_mfma_f32_16x16x32_f16(
              Pf[kt], hx[ci][sl], acc[ci][kt], 0, 0, 0);
    }
    __builtin_amdgcn_s_setprio(0);
  }

  // ---- epilogue: vlad partials. Swapped D layout:
  //      kc = kt*16 + quad*4 + r,  c = (2wv+ci)*16 + lm ----
  float* vb = vlad_out + (SLAB ? (size_t)bid : (size_t)n) * (K_ * C_);
#pragma unroll
  for (int ci = 0; ci < 2; ++ci) {
    const int c = (2 * wv + ci) * 16 + lm;
#pragma unroll
    for (int kt = 0; kt < 4; ++kt) {
      const int kc0 = kt * 16 + quad * 4;
#pragma unroll
      for (int r = 0; r < 4; ++r) {
        if (SLAB) {
          vb[(size_t)(kc0 + r) * C_ + c] = acc[ci][kt][r];
        } else {
          atomicAdd(vb + (size_t)(kc0 + r) * C_ + c, acc[ci][kt][r]);
        }
      }
    }
  }

  // ---- epilogue: asum (reduce quads via shfl, waves via sRed) ----
#pragma unroll
  for (int kt = 0; kt < 4; ++kt) {
    float v = accA[kt];
    v += __shfl_xor(v, 16);
    v += __shfl_xor(v, 32);
    if (quad == 0) sRed[wv * K_ + kt * 16 + lm] = v;
  }
  __syncthreads();
  if (tid < K_) {
    float s = sRed[tid] + sRed[K_ + tid] + sRed[2 * K_ + tid] + sRed[3 * K_ + tid];
    if (SLAB) asum_out[(size_t)bid * K_ + tid] = s;
    else atomicAdd(asum_out + n * K_ + tid, s);
  }
}

// ---------------------------------------------------------------------------
// Kernel 2: reduce slabs, subtract asum*centroid, intra-normalize, gnorm
// ---------------------------------------------------------------------------
template <bool SLAB>
__global__ __launch_bounds__(128) void vlad_intra(
    const float* __restrict__ vlad_in, const float* __restrict__ asum_in,
    const float* __restrict__ cent, float* __restrict__ vlad_norm,
    float* __restrict__ gnorm) {
  const int bid = blockIdx.x;
  const int n = bid >> 6, k = bid & 63;
  const int c = threadIdx.x;

  float v, a;
  if (SLAB) {
    v = 0.f; a = 0.f;
#pragma unroll 4
    for (int ch = 0; ch < NBPN; ++ch) {
      v += vlad_in[((size_t)(n * NBPN + ch) * K_ + k) * C_ + c];
      a += asum_in[(n * NBPN + ch) * K_ + k];
    }
  } else {
    v = vlad_in[((size_t)(n * K_ + k)) * C_ + c];
    a = asum_in[n * K_ + k];
  }
  v -= a * cent[k * C_ + c];

  float ss = v * v;
  ss += __shfl_xor(ss, 1);  ss += __shfl_xor(ss, 2);  ss += __shfl_xor(ss, 4);
  ss += __shfl_xor(ss, 8);  ss += __shfl_xor(ss, 16); ss += __shfl_xor(ss, 32);
  __shared__ float red[2];
  if ((threadIdx.x & 63) == 0) red[threadIdx.x >> 6] = ss;
  __syncthreads();
  float total = red[0] + red[1];
  float nrm = fmaxf(sqrtf(total), EPS);
  vlad_norm[((size_t)(n * K_ + k)) * C_ + c] = v / nrm;
  if (threadIdx.x == 0) atomicAdd(gnorm + n, total / (nrm * nrm));
}

// ---------------------------------------------------------------------------
// Kernel 3: global L2 normalize per n
// ---------------------------------------------------------------------------
__global__ __launch_bounds__(256) void vlad_final(
    const float* __restrict__ vlad_norm, const float* __restrict__ gnorm,
    float* __restrict__ out) {
  const int idx = blockIdx.x * 256 + threadIdx.x;
  if (idx >= N_ * K_ * C_) return;
  float g = gnorm[idx >> 13];
  out[idx] = vlad_norm[idx] / fmaxf(sqrtf(g), EPS);
}

extern "C" void kernel_launch(void* const* d_in, const int* in_sizes, int n_in,
                              void* d_out, int out_size, void* d_ws, size_t ws_size,
                              hipStream_t stream) {
  const float* x    = (const float*)d_in[0];
  const float* w    = (const float*)d_in[1];
  const float* cent = (const float*)d_in[2];
  float* out = (float*)d_out;

  const size_t slab_f = (size_t)NBLK * K_ * C_;    // 8,388,608 floats (33.5 MB)
  const size_t asum_f = (size_t)NBLK * K_;         // 65,536
  const size_t norm_f = (size_t)N_ * K_ * C_;      // 262,144
  const size_t need = (slab_f + asum_f + norm_f + N_) * sizeof(float);

  if (ws_size >= need) {
    float* slab  = (float*)d_ws;
    float* asums = slab + slab_f;
    float* vnorm = asums + asum_f;
    float* gnorm = vnorm + norm_f;
    hipMemsetAsync(gnorm, 0, N_ * sizeof(float), stream);
    vlad_main<true><<<dim3(NBLK), dim3(256), 0, stream>>>(x, w, slab, asums);
    vlad_intra<true><<<dim3(N_ * K_), dim3(128), 0, stream>>>(slab, asums, cent, vnorm, gnorm);
    vlad_final<<<dim3((N_ * K_ * C_ + 255) / 256), dim3(256), 0, stream>>>(vnorm, gnorm, out);
  } else {
    float* vlad_acc = (float*)d_ws;
    float* asum_g   = vlad_acc + norm_f;
    float* gnorm    = asum_g + N_ * K_;
    hipMemsetAsync(d_ws, 0, (norm_f + N_ * K_ + N_) * sizeof(float), stream);
    vlad_main<false><<<dim3(NBLK), dim3(256), 0, stream>>>(x, w, vlad_acc, asum_g);
    vlad_intra<false><<<dim3(N_ * K_), dim3(128), 0, stream>>>(vlad_acc, asum_g, cent, vlad_acc, gnorm);
    vlad_final<<<dim3((N_ * K_ * C_ + 255) / 256), dim3(256), 0, stream>>>(vlad_acc, gnorm, out);
  }
}